// Round 2
// baseline (775.444 us; speedup 1.0000x reference)
//
#include <hip/hip_runtime.h>
#include <math.h>

#define NPTS 400000
#define K27  27

typedef unsigned short u16;
typedef __bf16 bf16x8 __attribute__((ext_vector_type(8)));
typedef float  f32x4  __attribute__((ext_vector_type(4)));

__device__ __forceinline__ u16 f2bf(float f) {
    unsigned u = __float_as_uint(f);
    u += 0x7FFFu + ((u >> 16) & 1u);   // RNE round to bf16
    return (u16)(u >> 16);
}
__device__ __forceinline__ unsigned pack2(float lo, float hi) {
    return (unsigned)f2bf(lo) | ((unsigned)f2bf(hi) << 16);
}
__device__ __forceinline__ bf16x8 pack8(float4 x, float4 y) {
    union { uint4 u; bf16x8 v; } r;
    r.u.x = pack2(x.x, x.y); r.u.y = pack2(x.z, x.w);
    r.u.z = pack2(y.x, y.y); r.u.w = pack2(y.z, y.w);
    return r.v;
}
__device__ __forceinline__ bf16x8 zero8() {
    union { uint4 u; bf16x8 v; } r;
    r.u.x = 0; r.u.y = 0; r.u.z = 0; r.u.w = 0;
    return r.v;
}

// ---------------------------------------------------------------------------
// prep: transpose+pad W1 [27][64][38] -> W1t [27][48][64] bf16 (n-major, k-contig)
//       and W2 [27][38][38] -> W2t [27][48][64] bf16, zero-padded.
// Also zeroes the padding row (index NPTS) of h and Fb so the gather path
// needs no branch: idx==NPTS reads a zero row.
// ---------------------------------------------------------------------------
__global__ void prep_w(const float* __restrict__ W1, const float* __restrict__ W2,
                       u16* __restrict__ W1t, u16* __restrict__ W2t,
                       u16* __restrict__ hpad, u16* __restrict__ fpad)
{
    int i = blockIdx.x * 256 + threadIdx.x;
    if (i < 64) {                 // one 64-short row each
        hpad[i] = 0;
        if (fpad) fpad[i] = 0;
    }
    const int TOT = K27 * 48 * 64;
    if (i >= TOT) return;
    int k  = i / (48 * 64);
    int r  = i % (48 * 64);
    int n  = r >> 6;    // 0..47 (out channel)
    int kc = r & 63;    // 0..63 (in channel)
    u16 w1 = 0, w2 = 0;
    if (n < 38) {
        w1 = f2bf(W1[(k * 64 + kc) * 38 + n]);
        if (kc < 38) w2 = f2bf(W2[(k * 38 + kc) * 38 + n]);
    }
    W1t[i] = w1;
    W2t[i] = w2;
}

// ---------------------------------------------------------------------------
// prep: features fp32 [N][64] -> bf16 [N][64]  (8 elems / thread)
// ---------------------------------------------------------------------------
__global__ void prep_feat(const float* __restrict__ F, u16* __restrict__ Fb)
{
    size_t i = (size_t)blockIdx.x * 256 + threadIdx.x;
    const size_t TOT = (size_t)NPTS * 64 / 8;              // 3,200,000 exact
    if (i >= TOT) return;
    const float4* fp = (const float4*)(F + i * 8);
    float4 a = fp[0], b = fp[1];
    uint4 v;
    v.x = pack2(a.x, a.y); v.y = pack2(a.z, a.w);
    v.z = pack2(b.x, b.y); v.w = pack2(b.z, b.w);
    *(uint4*)(Fb + i * 8) = v;
}

// ---------------------------------------------------------------------------
// gather-GEMM layer, LDS-free / barrier-free, register-double-buffered.
// Block = 256 threads (4 waves); each wave owns 32 rows (2 row-tiles of 16).
// Pipeline (per k): gather A_{k+1} into ping/pong regs using idx prefetched
// one iter ago; load idx[k+2]; load B_k (L1-hot); MFMA on A_k.
// LAYER==1: -> GELU -> h bf16 [N+1][64] (cols 48..63 zeroed)
// LAYER==2: -> fp32 out [N][38]
// ---------------------------------------------------------------------------
template<int LAYER, bool BF16IN>
__global__ __launch_bounds__(256, 4)
void spconv(const void* __restrict__ in_, const int* __restrict__ nbr,
            const u16* __restrict__ Wt, void* __restrict__ out_)
{
    const int t     = threadIdx.x;
    const int wave  = t >> 6;
    const int lane  = t & 63;
    const int quad  = lane >> 4;
    const int l16   = lane & 15;
    const int rbase = blockIdx.x * 128 + wave * 32;   // 3125*128 == 400000

    f32x4 acc[2][3] = {};

    bf16x8 aC[2][2], aN[2][2];     // ping/pong A fragments
    int idxP[2], idxQ[2];          // ping/pong neighbor indices

    // prologue: idx[0] -> gather A_0 into aC; idx[1] into idxQ
    idxP[0] = nbr[rbase + l16];
    idxP[1] = nbr[rbase + 16 + l16];

    #define GATHER_BF16(dst, ids)                                             \
        {                                                                     \
            const u16* F = (const u16*)in_;                                   \
            _Pragma("unroll")                                                 \
            for (int rt = 0; rt < 2; ++rt) {                                  \
                const u16* rowp = F + (size_t)(ids)[rt] * 64 + quad * 8;      \
                (dst)[rt][0] = *(const bf16x8*)(rowp);                        \
                (dst)[rt][1] = *(const bf16x8*)(rowp + 32);                   \
            }                                                                 \
        }
    #define GATHER_F32(dst, ids)                                              \
        {                                                                     \
            const float* F = (const float*)in_;                               \
            _Pragma("unroll")                                                 \
            for (int rt = 0; rt < 2; ++rt) {                                  \
                if ((ids)[rt] < NPTS) {                                       \
                    const float* rowp = F + (size_t)(ids)[rt] * 64 + quad * 8;\
                    float4 f0 = *(const float4*)(rowp);                       \
                    float4 f1 = *(const float4*)(rowp + 4);                   \
                    float4 f2 = *(const float4*)(rowp + 32);                  \
                    float4 f3 = *(const float4*)(rowp + 36);                  \
                    (dst)[rt][0] = pack8(f0, f1);                             \
                    (dst)[rt][1] = pack8(f2, f3);                             \
                } else {                                                      \
                    (dst)[rt][0] = zero8();                                   \
                    (dst)[rt][1] = zero8();                                   \
                }                                                             \
            }                                                                 \
        }
    #define GATHER(dst, ids) { if (BF16IN) GATHER_BF16(dst, ids) else GATHER_F32(dst, ids) }

    GATHER(aC, idxP);
    idxQ[0] = nbr[(size_t)NPTS + rbase + l16];
    idxQ[1] = nbr[(size_t)NPTS + rbase + 16 + l16];

    const u16* wk = Wt + (size_t)(l16 * 64 + quad * 8);   // per-lane W base, k=0

    // body(k): consume acur/B_k, prefetch A_{k+1} (via iq) into anxt, idx[k+2] into ip
    auto body = [&](int k, bf16x8 (&acur)[2][2], bf16x8 (&anxt)[2][2],
                    int (&iq)[2], int (&ip)[2]) {
        // B_k fragments (L1-hot: same 6KB for every wave)
        bf16x8 b[3][2];
        #pragma unroll
        for (int nt = 0; nt < 3; ++nt) {
            b[nt][0] = *(const bf16x8*)(wk + nt * 1024);
            b[nt][1] = *(const bf16x8*)(wk + nt * 1024 + 32);
        }
        // prefetch A_{k+1} (iq was loaded one full iteration ago)
        if (k + 1 < K27) GATHER(anxt, iq);
        // prefetch idx[k+2]
        if (k + 2 < K27) {
            const int* nr = nbr + (size_t)(k + 2) * NPTS + rbase;
            ip[0] = nr[l16];
            ip[1] = nr[16 + l16];
        }
        // 12 MFMAs on the current (already-resident) fragments
        #pragma unroll
        for (int ks = 0; ks < 2; ++ks)
            #pragma unroll
            for (int rt = 0; rt < 2; ++rt)
                #pragma unroll
                for (int nt = 0; nt < 3; ++nt)
                    acc[rt][nt] = __builtin_amdgcn_mfma_f32_16x16x32_bf16(
                        acur[rt][ks], b[nt][ks], acc[rt][nt], 0, 0, 0);
        wk += 48 * 64;
    };

    for (int k = 0; k + 1 < K27; k += 2) {   // 13 pairs: k = 0..25
        body(k,     aC, aN, idxQ, idxP);
        body(k + 1, aN, aC, idxP, idxQ);
    }
    body(K27 - 1, aC, aN, idxQ, idxP);       // k = 26

    // ---- epilogue (C layout: col = l16, row = quad*4 + r) ----
    if (LAYER == 1) {
        u16* h = (u16*)out_;
        #pragma unroll
        for (int rt = 0; rt < 2; ++rt) {
            #pragma unroll
            for (int r = 0; r < 4; ++r) {
                size_t ro = (size_t)(rbase + rt * 16 + quad * 4 + r) * 64;
                #pragma unroll
                for (int nt = 0; nt < 3; ++nt) {
                    float x = acc[rt][nt][r];
                    float g = 0.5f * x * (1.0f + erff(x * 0.70710678118654752f));
                    h[ro + nt * 16 + l16] = f2bf(g);
                }
                h[ro + 48 + l16] = 0;      // zero pad cols 48..63
            }
        }
    } else {
        float* out = (float*)out_;
        #pragma unroll
        for (int rt = 0; rt < 2; ++rt) {
            #pragma unroll
            for (int nt = 0; nt < 3; ++nt) {
                int col = nt * 16 + l16;
                if (col < 38) {
                    #pragma unroll
                    for (int r = 0; r < 4; ++r) {
                        int row = rbase + rt * 16 + quad * 4 + r;
                        out[(size_t)row * 38 + col] = acc[rt][nt][r];
                    }
                }
            }
        }
    }
    #undef GATHER
    #undef GATHER_BF16
    #undef GATHER_F32
}

// ---------------------------------------------------------------------------
extern "C" void kernel_launch(void* const* d_in, const int* in_sizes, int n_in,
                              void* d_out, int out_size, void* d_ws, size_t ws_size,
                              hipStream_t stream)
{
    const float* feat = (const float*)d_in[0];   // [N][64] fp32
    const int*   nbr  = (const int*)  d_in[1];   // [27][N] int32, N == pad idx
    const float* W1   = (const float*)d_in[2];   // [27][64][38]
    const float* W2   = (const float*)d_in[3];   // [27][38][38]

    const size_t hbytes = (size_t)(NPTS + 1) * 64 * 2;   // h incl. zero pad row
    const size_t wbytes = (size_t)K27 * 48 * 64 * 2;     // 165,888

    char* ws  = (char*)d_ws;
    u16* h    = (u16*)ws;
    u16* W1t  = (u16*)(ws + hbytes);
    u16* W2t  = (u16*)(ws + hbytes + wbytes);
    u16* Fb   = (u16*)(ws + hbytes + 2 * wbytes);
    const bool full = ws_size >= hbytes * 2 + 2 * wbytes;   // bf16 feature copy fits?

    prep_w<<<(K27 * 48 * 64 + 255) / 256, 256, 0, stream>>>(
        W1, W2, W1t, W2t,
        h + (size_t)NPTS * 64,
        full ? Fb + (size_t)NPTS * 64 : (u16*)nullptr);

    const int nblk = NPTS / 128;   // 3125, exact
    if (full) {
        prep_feat<<<(int)(((size_t)NPTS * 64 / 8 + 255) / 256), 256, 0, stream>>>(feat, Fb);
        spconv<1, true ><<<nblk, 256, 0, stream>>>(Fb,   nbr, W1t, h);
    } else {
        spconv<1, false><<<nblk, 256, 0, stream>>>(feat, nbr, W1t, h);
    }
    spconv<2, true ><<<nblk, 256, 0, stream>>>(h, nbr, W2t, d_out);
}